// Round 6
// baseline (214.641 us; speedup 1.0000x reference)
//
#include <hip/hip_runtime.h>
#include <hip/hip_bf16.h>
#include <cstddef>
#include <cstdint>

#define NROWS 8192
#define LOG2E 1.4426950408889634f

typedef __attribute__((ext_vector_type(8))) short bf16x8;
typedef __attribute__((ext_vector_type(4))) float f32x4;

#define EXP2(x) __builtin_amdgcn_exp2f(x)

__device__ __forceinline__ short f2bf(float f) {
  unsigned u = __float_as_uint(f);
  u += 0x7fffu + ((u >> 16) & 1u);   // RNE
  return (short)(u >> 16);
}
__device__ __forceinline__ float leaky_f(float v) { return fmaxf(v, 0.1f * v); }

union BFPair { __hip_bfloat162 h; unsigned u; };
__device__ __forceinline__ unsigned pack2(float a, float b) {
  BFPair p;
  p.h = __float22bfloat162_rn(make_float2(a, b));  // -> v_cvt_pk_bf16_f32
  return p.u;
}

// ---------------- Kernel 1: MLP encoder: x[8192,256] -> x2, s(prescaled), sq, x2bfT --
extern "C" __global__ void __launch_bounds__(256)
encoder_kernel(const float* __restrict__ x, const float* __restrict__ W10,
               const float* __restrict__ b10, const float* __restrict__ W11,
               const float* __restrict__ b11, const float* __restrict__ avec,
               float* __restrict__ x2, float* __restrict__ sarr,
               float* __restrict__ sqarr, short* __restrict__ x2bfT) {
  __shared__ float xr[4][256];
  __shared__ float h1[4][128];
  const int t = threadIdx.x;
  const int r0 = blockIdx.x * 4;
#pragma unroll
  for (int r = 0; r < 4; ++r) xr[r][t] = x[(size_t)(r0 + r) * 256 + t];
  __syncthreads();
  if (t < 128) {
    float acc[4];
    const float b = b10[t];
#pragma unroll
    for (int r = 0; r < 4; ++r) acc[r] = b;
    const float* wrow = W10 + t * 256;
    for (int c = 0; c < 256; c += 4) {
      const float4 wv = *(const float4*)(wrow + c);
#pragma unroll
      for (int r = 0; r < 4; ++r) {
        acc[r] = fmaf(wv.x, xr[r][c], acc[r]);
        acc[r] = fmaf(wv.y, xr[r][c + 1], acc[r]);
        acc[r] = fmaf(wv.z, xr[r][c + 2], acc[r]);
        acc[r] = fmaf(wv.w, xr[r][c + 3], acc[r]);
      }
    }
#pragma unroll
    for (int r = 0; r < 4; ++r) h1[r][t] = leaky_f(acc[r]);
  }
  __syncthreads();
  if (t < 64) {
    float acc[4];
    const float b = b11[t];
#pragma unroll
    for (int r = 0; r < 4; ++r) acc[r] = b;
    const float* wrow = W11 + t * 128;
    for (int c = 0; c < 128; c += 4) {
      const float4 wv = *(const float4*)(wrow + c);
#pragma unroll
      for (int r = 0; r < 4; ++r) {
        acc[r] = fmaf(wv.x, h1[r][c], acc[r]);
        acc[r] = fmaf(wv.y, h1[r][c + 1], acc[r]);
        acc[r] = fmaf(wv.z, h1[r][c + 2], acc[r]);
        acc[r] = fmaf(wv.w, h1[r][c + 3], acc[r]);
      }
    }
    const float av = avec[t];
#pragma unroll
    for (int r = 0; r < 4; ++r) {
      const float v = leaky_f(acc[r]);
      x2[(size_t)(r0 + r) * 64 + t] = v;
      x2bfT[(size_t)t * NROWS + r0 + r] = f2bf(v);
      float ps = v * av, pq = v * v;
#pragma unroll
      for (int off = 1; off < 64; off <<= 1) {
        ps += __shfl_xor(ps, off);
        pq += __shfl_xor(pq, off);
      }
      if (t == 0) {
        sarr[r0 + r] = ps * LOG2E;          // prescaled: exp(leaky(d)) = exp2(leaky(d*log2e))
        sqarr[r0 + r] = pq * (1.0f / 64.0f);
      }
    }
  }
}

// ---------------- Kernel 1b: pre-swizzle B fragments into contiguous layout ---------
// Bfrag[S][nf][lane][8] (bf16): value = x2^T[n = nf*16 + (lane&15)][k = S*32 + (lane>>4)*8 + e]
// Ext[S][lane][8]: col0 = 1.0, col1 = sq_k, else 0  (rowsum & wsq folded into MFMA)
extern "C" __global__ void __launch_bounds__(256)
prep_kernel(const short* __restrict__ x2bfT, const float* __restrict__ sqarr,
            short* __restrict__ Bfrag, short* __restrict__ Ext) {
  const int S = blockIdx.x;           // 256 k-step groups of 32
  const int t = threadIdx.x;
  const int nf = t >> 6, l = t & 63;
  const int fr = l & 15, kg = l >> 4;
  const bf16x8 v = *(const bf16x8*)(x2bfT + (size_t)(nf * 16 + fr) * NROWS + S * 32 + kg * 8);
  *(bf16x8*)(Bfrag + ((size_t)S * 4 + nf) * 512 + l * 8) = v;
  if (nf == 0) {
    bf16x8 e;
    if (fr == 0) {
#pragma unroll
      for (int i = 0; i < 8; ++i) e[i] = (short)0x3F80;      // bf16 1.0
    } else if (fr == 1) {
#pragma unroll
      for (int i = 0; i < 8; ++i) e[i] = f2bf(sqarr[S * 32 + kg * 8 + i]);
    } else {
#pragma unroll
      for (int i = 0; i < 8; ++i) e[i] = 0;
    }
    *(bf16x8*)(Ext + (size_t)S * 512 + l * 8) = e;
  }
}

// ---------------- Kernel 2: fused A-pass, wave-private, fully linear loads ----------
// Wave owns 16 rows; per 256-j chunk: 16 contiguous 1KB row-loads (rolling, 16-deep),
// exp in regs, bf16 -> wave-private XOR-swizzled LDS, MFMA (4 y-frags + ext + diag).
// No barriers. One vmcnt(0) per chunk at the pipeline-empty point.

#define LDGX4(dst, sbase, voff) \
  asm volatile("global_load_dwordx4 %0, %1, %2" \
               : "=&v"(dst) : "v"(voff), "s"(sbase) : "memory")

extern "C" __global__ void __launch_bounds__(256, 2)
fused_attn_kernel(const float* __restrict__ A, const float* __restrict__ sarr,
                  const short* __restrict__ Bfrag, const short* __restrict__ Ext,
                  float* __restrict__ yp, float* __restrict__ rsp,
                  float* __restrict__ ssp, float* __restrict__ wsp, int jspan) {
  __shared__ short lraw[4][4096];     // per-wave [16][256] bf16, XOR-swizzled
  const int t = threadIdx.x;
  const int l = t & 63;
  const int w = __builtin_amdgcn_readfirstlane(t >> 6);
  const int fr = l & 15, kg = l >> 4;
  const int bi = blockIdx.x & 127, js = blockIdx.x >> 7;
  const int i0 = bi * 64;
  const int jb = js * jspan;
  const int nch = jspan >> 8;
  const int irow0 = i0 + w * 16;

  float si[16];
#pragma unroll
  for (int r = 0; r < 16; ++r) si[r] = sarr[irow0 + r];    // uniform -> scalar loads

  uint64_t rb[16];
#pragma unroll
  for (int r = 0; r < 16; ++r)
    rb[r] = (uint64_t)(const void*)(A + (size_t)(irow0 + r) * NROWS + jb);

  unsigned voff = (unsigned)(l * 16);

  f32x4 acc_y0 = {0.f,0.f,0.f,0.f}, acc_y1 = {0.f,0.f,0.f,0.f};
  f32x4 acc_y2 = {0.f,0.f,0.f,0.f}, acc_y3 = {0.f,0.f,0.f,0.f};
  f32x4 acc_e  = {0.f,0.f,0.f,0.f}, acc_d  = {0.f,0.f,0.f,0.f};

  f32x4 ab[16];
#pragma unroll
  for (int r = 0; r < 16; ++r) LDGX4(ab[r], rb[r], voff);   // prologue: chunk 0

  short* myl = lraw[w];

#pragma unroll 1
  for (int ch = 0; ch < nch; ++ch) {
    // pipeline-empty drain point: next chunk's loads not yet issued
    asm volatile("s_waitcnt vmcnt(0)" ::: "memory");
    __builtin_amdgcn_sched_barrier(0);

    const f32x4 sjv = *(const f32x4*)(sarr + jb + ch * 256 + l * 4);
    const unsigned voff_n = voff + 1024;
    const bool more = (ch + 1 < nch);

    // exp phase: consume chunk ch, roll-issue chunk ch+1 into the same regs
#pragma unroll
    for (int r = 0; r < 16; ++r) {
      const f32x4 a4 = ab[r];
      const float sv = si[r];
      const float d0 = sv - sjv[0], d1 = sv - sjv[1];
      const float d2 = sv - sjv[2], d3 = sv - sjv[3];
      const float r0 = EXP2(fmaxf(d0, 0.1f * d0)) * a4[0];
      const float r1 = EXP2(fmaxf(d1, 0.1f * d1)) * a4[1];
      const float r2 = EXP2(fmaxf(d2, 0.1f * d2)) * a4[2];
      const float r3 = EXP2(fmaxf(d3, 0.1f * d3)) * a4[3];
      uint2 pk;
      pk.x = pack2(r0, r1);
      pk.y = pack2(r2, r3);
      const int kb = (l * 8) ^ ((r & 7) << 4);               // swizzled byte offset
      *(uint2*)(myl + r * 256 + (kb >> 1)) = pk;
      if (more) LDGX4(ab[r], rb[r], voff_n);
    }

    // MFMA phase: 8 k-steps x (A-frag ds_read + 5 contiguous B/Ext loads + 6 MFMA)
    const int Sg0 = (jb >> 5) + ch * 8;
#pragma unroll
    for (int s = 0; s < 8; ++s) {
      const int kb = (s * 64 + kg * 16) ^ ((fr & 7) << 4);
      const bf16x8 ar = *(const bf16x8*)(myl + fr * 256 + (kb >> 1));
      const short* bp = Bfrag + (size_t)(Sg0 + s) * 2048 + l * 8;
      const bf16x8 b0 = *(const bf16x8*)(bp);
      const bf16x8 b1 = *(const bf16x8*)(bp + 512);
      const bf16x8 b2 = *(const bf16x8*)(bp + 1024);
      const bf16x8 b3 = *(const bf16x8*)(bp + 1536);
      const bf16x8 ef = *(const bf16x8*)(Ext + (size_t)(Sg0 + s) * 512 + l * 8);
      acc_y0 = __builtin_amdgcn_mfma_f32_16x16x32_bf16(ar, b0, acc_y0, 0, 0, 0);
      acc_y1 = __builtin_amdgcn_mfma_f32_16x16x32_bf16(ar, b1, acc_y1, 0, 0, 0);
      acc_y2 = __builtin_amdgcn_mfma_f32_16x16x32_bf16(ar, b2, acc_y2, 0, 0, 0);
      acc_y3 = __builtin_amdgcn_mfma_f32_16x16x32_bf16(ar, b3, acc_y3, 0, 0, 0);
      acc_e  = __builtin_amdgcn_mfma_f32_16x16x32_bf16(ar, ef, acc_e, 0, 0, 0);
      acc_d  = __builtin_amdgcn_mfma_f32_16x16x32_bf16(ar, ar, acc_d, 0, 0, 0);
    }
    voff = voff_n;
  }

  // epilogue: C/D layout col = lane&15, row = (lane>>4)*4 + reg
  float* ypb = yp + (size_t)js * NROWS * 64;
  const f32x4 accs[4] = {acc_y0, acc_y1, acc_y2, acc_y3};
#pragma unroll
  for (int nf = 0; nf < 4; ++nf)
#pragma unroll
    for (int ri = 0; ri < 4; ++ri)
      ypb[(size_t)(i0 + w * 16 + kg * 4 + ri) * 64 + nf * 16 + fr] = accs[nf][ri];
#pragma unroll
  for (int ri = 0; ri < 4; ++ri) {
    const int gi = i0 + w * 16 + kg * 4 + ri;
    if (fr == 0) rsp[js * NROWS + gi] = acc_e[ri];          // rowsum
    if (fr == 1) wsp[js * NROWS + gi] = acc_e[ri];          // wsq
    if (fr == kg * 4 + ri) ssp[js * NROWS + gi] = acc_d[ri]; // sumsq (diag of raw.raw^T)
  }
}

// ---------------- Kernel 3: combine partials, GNN layer + head, per-row losses ------
extern "C" __global__ void __launch_bounds__(256)
finish_kernel(const float* __restrict__ x2, const float* __restrict__ sqarr,
              const float* __restrict__ yp, const float* __restrict__ rsp,
              const float* __restrict__ ssp, const float* __restrict__ wsp,
              const float* __restrict__ Wg, const float* __restrict__ bg,
              const float* __restrict__ W2, const float* __restrict__ b2,
              float* __restrict__ outp, float* __restrict__ l1c, float* __restrict__ l2c,
              int jsplit) {
  __shared__ float hbuf[4][64];
  __shared__ float gbuf[4][64];
  const int t = threadIdx.x;
  const int w = t >> 6, lane = t & 63;
  const int i = blockIdx.x * 4 + w;

  float yv = 0.f, rowsum = 0.f, sumsq = 0.f, wsq = 0.f;
#pragma unroll 4
  for (int p = 0; p < jsplit; ++p) {
    yv += yp[(size_t)p * NROWS * 64 + (size_t)i * 64 + lane];
    rowsum += rsp[p * NROWS + i];
    sumsq += ssp[p * NROWS + i];
    wsq += wsp[p * NROWS + i];
  }
  const float inv = 1.0f / rowsum;
  hbuf[w][lane] = yv * inv;
  const float xv = x2[(size_t)i * 64 + lane];
  float xy = xv * yv;
#pragma unroll
  for (int off = 1; off < 64; off <<= 1) xy += __shfl_xor(xy, off);
  if (lane == 0) {
    l1c[i] = sqarr[i] + (wsq - (2.0f / 64.0f) * xy) * inv;
    l2c[i] = sumsq * inv * inv;
  }
  __syncthreads();
  float accg = bg[lane];
  {
    const float* wrow = Wg + lane * 64;
#pragma unroll 4
    for (int d = 0; d < 64; ++d) accg = fmaf(wrow[d], hbuf[w][d], accg);
  }
  gbuf[w][lane] = leaky_f(accg);
  __syncthreads();
  if (lane < 32) {
    float acco = b2[lane];
    const float* wrow = W2 + lane * 64;
#pragma unroll 4
    for (int d = 0; d < 64; ++d) acco = fmaf(wrow[d], gbuf[w][d], acco);
    outp[(size_t)i * 32 + lane] = acco;
  }
}

// ---------------- Kernel 4: scalar loss reduction -----------------------------------
extern "C" __global__ void __launch_bounds__(256)
loss_kernel(const float* __restrict__ l1c, const float* __restrict__ l2c,
            float* __restrict__ outp) {
  __shared__ float s1[256], s2[256];
  const int t = threadIdx.x;
  float a1 = 0.f, a2 = 0.f;
  for (int i = t * 4; i < NROWS; i += 1024) {
    const float4 v1 = *(const float4*)(l1c + i);
    const float4 v2 = *(const float4*)(l2c + i);
    a1 += (v1.x + v1.y) + (v1.z + v1.w);
    a2 += (v2.x + v2.y) + (v2.z + v2.w);
  }
  s1[t] = a1; s2[t] = a2;
  __syncthreads();
  for (int off = 128; off > 0; off >>= 1) {
    if (t < off) { s1[t] += s1[t + off]; s2[t] += s2[t + off]; }
    __syncthreads();
  }
  if (t == 0) {
    const float scale = 1.0f / ((float)NROWS * (float)NROWS);
    outp[NROWS * 32] = s1[0] * scale;
    outp[NROWS * 32 + 1] = s2[0] * scale;
  }
}

// ---------------- launch ------------------------------------------------------------
extern "C" void kernel_launch(void* const* d_in, const int* in_sizes, int n_in,
                              void* d_out, int out_size, void* d_ws, size_t ws_size,
                              hipStream_t stream) {
  const float* x   = (const float*)d_in[0];
  const float* A   = (const float*)d_in[1];
  const float* W10 = (const float*)d_in[2];
  const float* b10 = (const float*)d_in[3];
  const float* W11 = (const float*)d_in[4];
  const float* b11 = (const float*)d_in[5];
  const float* av  = (const float*)d_in[6];
  const float* Wg  = (const float*)d_in[7];
  const float* bg  = (const float*)d_in[8];
  const float* W2  = (const float*)d_in[9];
  const float* b2  = (const float*)d_in[10];
  float* out = (float*)d_out;

  const size_t fixed_floats = (size_t)NROWS * 64 + 4 * (size_t)NROWS;
  auto need = [&](int js) {
    return (fixed_floats + (size_t)js * NROWS * 64 + 3 * (size_t)js * NROWS) * 4
           + (size_t)NROWS * 64 * 2      // x2bfT
           + (size_t)256 * 2048 * 2      // Bfrag
           + (size_t)256 * 512 * 2;      // Ext
  };
  const int jsplit = (ws_size >= need(8)) ? 8 : 4;
  const int jspan = NROWS / jsplit;

  float* ws    = (float*)d_ws;
  float* x2    = ws;                                        // N*64
  float* sarr  = x2 + (size_t)NROWS * 64;                   // N (prescaled by log2 e)
  float* sqarr = sarr + NROWS;                              // N
  float* yp    = sqarr + NROWS;                             // jsplit*N*64
  float* rsp   = yp + (size_t)jsplit * NROWS * 64;          // jsplit*N
  float* ssp   = rsp + (size_t)jsplit * NROWS;              // jsplit*N
  float* wsp   = ssp + (size_t)jsplit * NROWS;              // jsplit*N
  float* l1c   = wsp + (size_t)jsplit * NROWS;              // N
  float* l2c   = l1c + NROWS;                               // N
  short* x2bfT = (short*)(l2c + NROWS);                     // N*64 bf16 (transposed)
  short* Bfrag = x2bfT + (size_t)NROWS * 64;                // 256*4*512 bf16 (1MB)
  short* Ext   = Bfrag + (size_t)256 * 2048;                // 256*512 bf16 (256KB)

  hipLaunchKernelGGL(encoder_kernel, dim3(2048), dim3(256), 0, stream,
                     x, W10, b10, W11, b11, av, x2, sarr, sqarr, x2bfT);
  hipLaunchKernelGGL(prep_kernel, dim3(256), dim3(256), 0, stream,
                     x2bfT, sqarr, Bfrag, Ext);
  hipLaunchKernelGGL(fused_attn_kernel, dim3(128 * jsplit), dim3(256), 0, stream,
                     A, sarr, Bfrag, Ext, yp, rsp, ssp, wsp, jspan);
  hipLaunchKernelGGL(finish_kernel, dim3(2048), dim3(256), 0, stream,
                     x2, sqarr, yp, rsp, ssp, wsp, Wg, bg, W2, b2, out, l1c, l2c, jsplit);
  hipLaunchKernelGGL(loss_kernel, dim3(1), dim3(256), 0, stream, l1c, l2c, out);
}

// Round 7
// 188.988 us; speedup vs baseline: 1.1357x; 1.1357x over previous
//
#include <hip/hip_runtime.h>
#include <hip/hip_bf16.h>
#include <cstddef>
#include <cstdint>

#define NROWS 8192
#define LOG2E 1.4426950408889634f

typedef __attribute__((ext_vector_type(8))) short bf16x8;
typedef __attribute__((ext_vector_type(4))) float f32x4;

#define EXP2(x) __builtin_amdgcn_exp2f(x)

__device__ __forceinline__ short f2bf(float f) {
  unsigned u = __float_as_uint(f);
  u += 0x7fffu + ((u >> 16) & 1u);   // RNE
  return (short)(u >> 16);
}
__device__ __forceinline__ float leaky_f(float v) { return fmaxf(v, 0.1f * v); }

union BFPair { __hip_bfloat162 h; unsigned u; };
__device__ __forceinline__ unsigned pack2(float a, float b) {
  BFPair p;
  p.h = __float22bfloat162_rn(make_float2(a, b));  // -> v_cvt_pk_bf16_f32
  return p.u;
}

// ---------------- Kernel 1: MLP encoder: x[8192,256] -> x2, s(prescaled), sq, x2bfT --
extern "C" __global__ void __launch_bounds__(256)
encoder_kernel(const float* __restrict__ x, const float* __restrict__ W10,
               const float* __restrict__ b10, const float* __restrict__ W11,
               const float* __restrict__ b11, const float* __restrict__ avec,
               float* __restrict__ x2, float* __restrict__ sarr,
               float* __restrict__ sqarr, short* __restrict__ x2bfT) {
  __shared__ float xr[4][256];
  __shared__ float h1[4][128];
  const int t = threadIdx.x;
  const int r0 = blockIdx.x * 4;
#pragma unroll
  for (int r = 0; r < 4; ++r) xr[r][t] = x[(size_t)(r0 + r) * 256 + t];
  __syncthreads();
  if (t < 128) {
    float acc[4];
    const float b = b10[t];
#pragma unroll
    for (int r = 0; r < 4; ++r) acc[r] = b;
    const float* wrow = W10 + t * 256;
    for (int c = 0; c < 256; c += 4) {
      const float4 wv = *(const float4*)(wrow + c);
#pragma unroll
      for (int r = 0; r < 4; ++r) {
        acc[r] = fmaf(wv.x, xr[r][c], acc[r]);
        acc[r] = fmaf(wv.y, xr[r][c + 1], acc[r]);
        acc[r] = fmaf(wv.z, xr[r][c + 2], acc[r]);
        acc[r] = fmaf(wv.w, xr[r][c + 3], acc[r]);
      }
    }
#pragma unroll
    for (int r = 0; r < 4; ++r) h1[r][t] = leaky_f(acc[r]);
  }
  __syncthreads();
  if (t < 64) {
    float acc[4];
    const float b = b11[t];
#pragma unroll
    for (int r = 0; r < 4; ++r) acc[r] = b;
    const float* wrow = W11 + t * 128;
    for (int c = 0; c < 128; c += 4) {
      const float4 wv = *(const float4*)(wrow + c);
#pragma unroll
      for (int r = 0; r < 4; ++r) {
        acc[r] = fmaf(wv.x, h1[r][c], acc[r]);
        acc[r] = fmaf(wv.y, h1[r][c + 1], acc[r]);
        acc[r] = fmaf(wv.z, h1[r][c + 2], acc[r]);
        acc[r] = fmaf(wv.w, h1[r][c + 3], acc[r]);
      }
    }
    const float av = avec[t];
#pragma unroll
    for (int r = 0; r < 4; ++r) {
      const float v = leaky_f(acc[r]);
      x2[(size_t)(r0 + r) * 64 + t] = v;
      x2bfT[(size_t)t * NROWS + r0 + r] = f2bf(v);
      float ps = v * av, pq = v * v;
#pragma unroll
      for (int off = 1; off < 64; off <<= 1) {
        ps += __shfl_xor(ps, off);
        pq += __shfl_xor(pq, off);
      }
      if (t == 0) {
        sarr[r0 + r] = ps * LOG2E;          // prescaled: exp(leaky(d)) = exp2(leaky(d*log2e))
        sqarr[r0 + r] = pq * (1.0f / 64.0f);
      }
    }
  }
}

// ---------------- Kernel 1b: pre-swizzle B fragments into contiguous layout ---------
// Bfrag[S][nf][lane][8] (bf16): value = x2^T[n = nf*16 + (lane&15)][k = S*32 + (lane>>4)*8 + e]
// Ext[S][lane][8]: col0 = 1.0, col1 = sq_k, else 0  (rowsum & wsq folded into MFMA)
extern "C" __global__ void __launch_bounds__(256)
prep_kernel(const short* __restrict__ x2bfT, const float* __restrict__ sqarr,
            short* __restrict__ Bfrag, short* __restrict__ Ext) {
  const int S = blockIdx.x;           // 256 k-step groups of 32
  const int t = threadIdx.x;
  const int nf = t >> 6, l = t & 63;
  const int fr = l & 15, kg = l >> 4;
  const bf16x8 v = *(const bf16x8*)(x2bfT + (size_t)(nf * 16 + fr) * NROWS + S * 32 + kg * 8);
  *(bf16x8*)(Bfrag + ((size_t)S * 4 + nf) * 512 + l * 8) = v;
  if (nf == 0) {
    bf16x8 e;
    if (fr == 0) {
#pragma unroll
      for (int i = 0; i < 8; ++i) e[i] = (short)0x3F80;      // bf16 1.0
    } else if (fr == 1) {
#pragma unroll
      for (int i = 0; i < 8; ++i) e[i] = f2bf(sqarr[S * 32 + kg * 8 + i]);
    } else {
#pragma unroll
      for (int i = 0; i < 8; ++i) e[i] = 0;
    }
    *(bf16x8*)(Ext + (size_t)S * 512 + l * 8) = e;
  }
}

// ---------------- Kernel 2: fused A-pass: global_load_lds + counted vmcnt -----------
// Wave owns 16 rows. Per 64-col tile: 10 contiguous B/Ext reg-loads (L2-hot), 4
// global_load_lds staging the NEXT tile (pre-swizzled source, linear LDS dest,
// zero VGPR cost), vmcnt(14) -> swizzled ds_read_b128 A-frag + exp2 + pack,
// vmcnt(4) -> 12 MFMA (stage stays in flight; never drain to 0). No barriers.

#define LDGB(dst, ptr, imm) \
  asm volatile("global_load_dwordx4 %0, %1, off offset:" imm \
               : "=&v"(dst) : "v"(ptr) : "memory")
#define VMCNT(imm) \
  do { asm volatile("s_waitcnt vmcnt(" imm ")" ::: "memory"); \
       __builtin_amdgcn_sched_barrier(0); } while (0)

#define STAGE(tt, buf) do {                                                          \
    char* dstb = (char*)Abuf[w] + (buf) * 4096;                                      \
    __builtin_amdgcn_global_load_lds(                                                \
        (const __attribute__((address_space(1))) void*)(sp0 + (tt) * 64),            \
        (__attribute__((address_space(3))) void*)(dstb), 16, 0, 0);                  \
    __builtin_amdgcn_global_load_lds(                                                \
        (const __attribute__((address_space(1))) void*)(sp1 + (tt) * 64),            \
        (__attribute__((address_space(3))) void*)(dstb + 1024), 16, 0, 0);           \
    __builtin_amdgcn_global_load_lds(                                                \
        (const __attribute__((address_space(1))) void*)(sp2 + (tt) * 64),            \
        (__attribute__((address_space(3))) void*)(dstb + 2048), 16, 0, 0);           \
    __builtin_amdgcn_global_load_lds(                                                \
        (const __attribute__((address_space(1))) void*)(sp3 + (tt) * 64),            \
        (__attribute__((address_space(3))) void*)(dstb + 3072), 16, 0, 0);           \
  } while (0)

#define EXPKS(c0, c1, s0, s1, dst) do {                         \
    const float d0 = sif - (s0)[0], d1 = sif - (s0)[1];         \
    const float d2 = sif - (s0)[2], d3 = sif - (s0)[3];         \
    const float d4 = sif - (s1)[0], d5 = sif - (s1)[1];         \
    const float d6 = sif - (s1)[2], d7 = sif - (s1)[3];         \
    const float r0 = EXP2(fmaxf(d0, 0.1f * d0)) * (c0)[0];      \
    const float r1 = EXP2(fmaxf(d1, 0.1f * d1)) * (c0)[1];      \
    const float r2 = EXP2(fmaxf(d2, 0.1f * d2)) * (c0)[2];      \
    const float r3 = EXP2(fmaxf(d3, 0.1f * d3)) * (c0)[3];      \
    const float r4 = EXP2(fmaxf(d4, 0.1f * d4)) * (c1)[0];      \
    const float r5 = EXP2(fmaxf(d5, 0.1f * d5)) * (c1)[1];      \
    const float r6 = EXP2(fmaxf(d6, 0.1f * d6)) * (c1)[2];      \
    const float r7 = EXP2(fmaxf(d7, 0.1f * d7)) * (c1)[3];      \
    union { bf16x8 v; unsigned u[4]; } pk;                      \
    pk.u[0] = pack2(r0, r1); pk.u[1] = pack2(r2, r3);           \
    pk.u[2] = pack2(r4, r5); pk.u[3] = pack2(r6, r7);           \
    dst = pk.v;                                                 \
  } while (0)

template <int NT>   // 64-col tiles per j-window
__global__ void __launch_bounds__(256, 4)
fused_attn_kernel(const float* __restrict__ A, const float* __restrict__ sarr,
                  const short* __restrict__ Bfrag, const short* __restrict__ Ext,
                  float* __restrict__ yp, float* __restrict__ rsp,
                  float* __restrict__ ssp, float* __restrict__ wsp) {
  __shared__ __attribute__((aligned(16))) char Abuf[4][2][4096];  // per-wave dbuf 16rx256B
  __shared__ __attribute__((aligned(16))) float sjbuf[NT * 64];
  __shared__ float sibuf[64];
  const int t = threadIdx.x;
  const int l = t & 63;
  const int w = __builtin_amdgcn_readfirstlane(t >> 6);
  const int fr = l & 15, kg = l >> 4, fr8 = fr & 7;
  const int bi = blockIdx.x & 127, js = blockIdx.x >> 7;
  const int i0 = bi * 64, jb = js * (NT * 64);
  const int irow0 = i0 + w * 16;
  const int lr = l >> 4, lc = l & 15;

  for (int k = t; k < NT * 64; k += 256) sjbuf[k] = sarr[jb + k];
  if (t < 64) sibuf[t] = sarr[i0 + t];
  __syncthreads();
  const float sif = sibuf[w * 16 + fr];

  // pre-swizzled per-lane stage sources: instr p covers rows p*4..p*4+3,
  // lane reads global 16B-chunk (lc ^ (row&7)) of its row  (XOR involution)
  const int r0_ = 0 * 4 + lr, r1_ = 1 * 4 + lr, r2_ = 2 * 4 + lr, r3_ = 3 * 4 + lr;
  const float* sp0 = A + (size_t)(irow0 + r0_) * NROWS + jb + ((lc ^ (r0_ & 7)) << 2);
  const float* sp1 = A + (size_t)(irow0 + r1_) * NROWS + jb + ((lc ^ (r1_ & 7)) << 2);
  const float* sp2 = A + (size_t)(irow0 + r2_) * NROWS + jb + ((lc ^ (r2_ & 7)) << 2);
  const float* sp3 = A + (size_t)(irow0 + r3_) * NROWS + jb + ((lc ^ (r3_ & 7)) << 2);

  const short* bq  = Bfrag + ((size_t)(jb >> 5)) * 2048 + l * 8;
  const short* bq2 = bq + 2048;
  const short* eq  = Ext + ((size_t)(jb >> 5)) * 512 + l * 8;

  f32x4 acc_y0 = {0.f,0.f,0.f,0.f}, acc_y1 = {0.f,0.f,0.f,0.f};
  f32x4 acc_y2 = {0.f,0.f,0.f,0.f}, acc_y3 = {0.f,0.f,0.f,0.f};
  f32x4 acc_e  = {0.f,0.f,0.f,0.f}, acc_d  = {0.f,0.f,0.f,0.f};

  STAGE(0, 0);   // prologue: tile 0 -> buf0 (4 outstanding)

#pragma unroll 1
  for (int tt = 0; tt < NT; ++tt) {
    bf16x8 b00, b01, b02, b03, b10, b11, b12, b13, e0, e1;
    LDGB(b00, bq, "0");  LDGB(b01, bq, "1024");
    LDGB(b02, bq, "2048"); LDGB(b03, bq, "3072");
    LDGB(e0, eq, "0");
    LDGB(b10, bq2, "0");  LDGB(b11, bq2, "1024");
    LDGB(b12, bq2, "2048"); LDGB(b13, bq2, "3072");
    LDGB(e1, eq, "1024");
    STAGE((tt + 1) & (NT - 1), (tt + 1) & 1);

    const float* sjp = sjbuf + tt * 64 + kg * 8;
    VMCNT("14");   // current tile's stage retired; 10 B + 4 next-stage in flight

    const char* ab = (const char*)Abuf[w] + (tt & 1) * 4096 + fr * 256;
    bf16x8 araw0, araw1;
    {
      const int g0 = kg * 2;
      const f32x4 c0 = *(const f32x4*)(ab + ((g0 ^ fr8) << 4));
      const f32x4 c1 = *(const f32x4*)(ab + (((g0 + 1) ^ fr8) << 4));
      const f32x4 s0 = *(const f32x4*)(sjp);
      const f32x4 s1 = *(const f32x4*)(sjp + 4);
      EXPKS(c0, c1, s0, s1, araw0);
    }
    {
      const int g0 = 8 + kg * 2;
      const f32x4 c0 = *(const f32x4*)(ab + ((g0 ^ fr8) << 4));
      const f32x4 c1 = *(const f32x4*)(ab + (((g0 + 1) ^ fr8) << 4));
      const f32x4 s0 = *(const f32x4*)(sjp + 32);
      const f32x4 s1 = *(const f32x4*)(sjp + 36);
      EXPKS(c0, c1, s0, s1, araw1);
    }
    VMCNT("4");    // B retired; next-tile stage (4 newest) stays in flight

    acc_y0 = __builtin_amdgcn_mfma_f32_16x16x32_bf16(araw0, b00, acc_y0, 0, 0, 0);
    acc_y1 = __builtin_amdgcn_mfma_f32_16x16x32_bf16(araw0, b01, acc_y1, 0, 0, 0);
    acc_y2 = __builtin_amdgcn_mfma_f32_16x16x32_bf16(araw0, b02, acc_y2, 0, 0, 0);
    acc_y3 = __builtin_amdgcn_mfma_f32_16x16x32_bf16(araw0, b03, acc_y3, 0, 0, 0);
    acc_e  = __builtin_amdgcn_mfma_f32_16x16x32_bf16(araw0, e0,  acc_e, 0, 0, 0);
    acc_d  = __builtin_amdgcn_mfma_f32_16x16x32_bf16(araw0, araw0, acc_d, 0, 0, 0);
    acc_y0 = __builtin_amdgcn_mfma_f32_16x16x32_bf16(araw1, b10, acc_y0, 0, 0, 0);
    acc_y1 = __builtin_amdgcn_mfma_f32_16x16x32_bf16(araw1, b11, acc_y1, 0, 0, 0);
    acc_y2 = __builtin_amdgcn_mfma_f32_16x16x32_bf16(araw1, b12, acc_y2, 0, 0, 0);
    acc_y3 = __builtin_amdgcn_mfma_f32_16x16x32_bf16(araw1, b13, acc_y3, 0, 0, 0);
    acc_e  = __builtin_amdgcn_mfma_f32_16x16x32_bf16(araw1, e1,  acc_e, 0, 0, 0);
    acc_d  = __builtin_amdgcn_mfma_f32_16x16x32_bf16(araw1, araw1, acc_d, 0, 0, 0);

    bq += 4096; bq2 += 4096; eq += 1024;
  }
  VMCNT("0");

  // epilogue: C/D layout col = lane&15, row = (lane>>4)*4 + reg
  float* ypb = yp + (size_t)js * NROWS * 64;
  const f32x4 accs[4] = {acc_y0, acc_y1, acc_y2, acc_y3};
#pragma unroll
  for (int nf = 0; nf < 4; ++nf)
#pragma unroll
    for (int ri = 0; ri < 4; ++ri)
      ypb[(size_t)(i0 + w * 16 + kg * 4 + ri) * 64 + nf * 16 + fr] = accs[nf][ri];
#pragma unroll
  for (int ri = 0; ri < 4; ++ri) {
    const int gi = i0 + w * 16 + kg * 4 + ri;
    if (fr == 0) rsp[js * NROWS + gi] = acc_e[ri];            // rowsum
    if (fr == 1) wsp[js * NROWS + gi] = acc_e[ri];            // wsq
    if (fr == kg * 4 + ri) ssp[js * NROWS + gi] = acc_d[ri];  // sumsq (diag)
  }
}

// ---------------- Kernel 3: combine partials, GNN layer + head, per-row losses ------
extern "C" __global__ void __launch_bounds__(256)
finish_kernel(const float* __restrict__ x2, const float* __restrict__ sqarr,
              const float* __restrict__ yp, const float* __restrict__ rsp,
              const float* __restrict__ ssp, const float* __restrict__ wsp,
              const float* __restrict__ Wg, const float* __restrict__ bg,
              const float* __restrict__ W2, const float* __restrict__ b2,
              float* __restrict__ outp, float* __restrict__ l1c, float* __restrict__ l2c,
              int jsplit) {
  __shared__ float hbuf[4][64];
  __shared__ float gbuf[4][64];
  const int t = threadIdx.x;
  const int w = t >> 6, lane = t & 63;
  const int i = blockIdx.x * 4 + w;

  float yv = 0.f, rowsum = 0.f, sumsq = 0.f, wsq = 0.f;
#pragma unroll 4
  for (int p = 0; p < jsplit; ++p) {
    yv += yp[(size_t)p * NROWS * 64 + (size_t)i * 64 + lane];
    rowsum += rsp[p * NROWS + i];
    sumsq += ssp[p * NROWS + i];
    wsq += wsp[p * NROWS + i];
  }
  const float inv = 1.0f / rowsum;
  hbuf[w][lane] = yv * inv;
  const float xv = x2[(size_t)i * 64 + lane];
  float xy = xv * yv;
#pragma unroll
  for (int off = 1; off < 64; off <<= 1) xy += __shfl_xor(xy, off);
  if (lane == 0) {
    l1c[i] = sqarr[i] + (wsq - (2.0f / 64.0f) * xy) * inv;
    l2c[i] = sumsq * inv * inv;
  }
  __syncthreads();
  float accg = bg[lane];
  {
    const float* wrow = Wg + lane * 64;
#pragma unroll 4
    for (int d = 0; d < 64; ++d) accg = fmaf(wrow[d], hbuf[w][d], accg);
  }
  gbuf[w][lane] = leaky_f(accg);
  __syncthreads();
  if (lane < 32) {
    float acco = b2[lane];
    const float* wrow = W2 + lane * 64;
#pragma unroll 4
    for (int d = 0; d < 64; ++d) acco = fmaf(wrow[d], gbuf[w][d], acco);
    outp[(size_t)i * 32 + lane] = acco;
  }
}

// ---------------- Kernel 4: scalar loss reduction -----------------------------------
extern "C" __global__ void __launch_bounds__(256)
loss_kernel(const float* __restrict__ l1c, const float* __restrict__ l2c,
            float* __restrict__ outp) {
  __shared__ float s1[256], s2[256];
  const int t = threadIdx.x;
  float a1 = 0.f, a2 = 0.f;
  for (int i = t * 4; i < NROWS; i += 1024) {
    const float4 v1 = *(const float4*)(l1c + i);
    const float4 v2 = *(const float4*)(l2c + i);
    a1 += (v1.x + v1.y) + (v1.z + v1.w);
    a2 += (v2.x + v2.y) + (v2.z + v2.w);
  }
  s1[t] = a1; s2[t] = a2;
  __syncthreads();
  for (int off = 128; off > 0; off >>= 1) {
    if (t < off) { s1[t] += s1[t + off]; s2[t] += s2[t + off]; }
    __syncthreads();
  }
  if (t == 0) {
    const float scale = 1.0f / ((float)NROWS * (float)NROWS);
    outp[NROWS * 32] = s1[0] * scale;
    outp[NROWS * 32 + 1] = s2[0] * scale;
  }
}

// ---------------- launch ------------------------------------------------------------
extern "C" void kernel_launch(void* const* d_in, const int* in_sizes, int n_in,
                              void* d_out, int out_size, void* d_ws, size_t ws_size,
                              hipStream_t stream) {
  const float* x   = (const float*)d_in[0];
  const float* A   = (const float*)d_in[1];
  const float* W10 = (const float*)d_in[2];
  const float* b10 = (const float*)d_in[3];
  const float* W11 = (const float*)d_in[4];
  const float* b11 = (const float*)d_in[5];
  const float* av  = (const float*)d_in[6];
  const float* Wg  = (const float*)d_in[7];
  const float* bg  = (const float*)d_in[8];
  const float* W2  = (const float*)d_in[9];
  const float* b2  = (const float*)d_in[10];
  float* out = (float*)d_out;

  const size_t fixed_floats = (size_t)NROWS * 64 + 4 * (size_t)NROWS;
  auto need = [&](int js) {
    return (fixed_floats + (size_t)js * NROWS * 64 + 3 * (size_t)js * NROWS) * 4
           + (size_t)NROWS * 64 * 2      // x2bfT
           + (size_t)256 * 2048 * 2      // Bfrag
           + (size_t)256 * 512 * 2;      // Ext
  };
  const int jsplit = (ws_size >= need(8)) ? 8 : 4;

  float* ws    = (float*)d_ws;
  float* x2    = ws;                                        // N*64
  float* sarr  = x2 + (size_t)NROWS * 64;                   // N (prescaled by log2 e)
  float* sqarr = sarr + NROWS;                              // N
  float* yp    = sqarr + NROWS;                             // jsplit*N*64
  float* rsp   = yp + (size_t)jsplit * NROWS * 64;          // jsplit*N
  float* ssp   = rsp + (size_t)jsplit * NROWS;              // jsplit*N
  float* wsp   = ssp + (size_t)jsplit * NROWS;              // jsplit*N
  float* l1c   = wsp + (size_t)jsplit * NROWS;              // N
  float* l2c   = l1c + NROWS;                               // N
  short* x2bfT = (short*)(l2c + NROWS);                     // N*64 bf16 (transposed)
  short* Bfrag = x2bfT + (size_t)NROWS * 64;                // 256*4*512 bf16 (1MB)
  short* Ext   = Bfrag + (size_t)256 * 2048;                // 256*512 bf16 (256KB)

  hipLaunchKernelGGL(encoder_kernel, dim3(2048), dim3(256), 0, stream,
                     x, W10, b10, W11, b11, av, x2, sarr, sqarr, x2bfT);
  hipLaunchKernelGGL(prep_kernel, dim3(256), dim3(256), 0, stream,
                     x2bfT, sqarr, Bfrag, Ext);
  if (jsplit == 8) {
    hipLaunchKernelGGL((fused_attn_kernel<16>), dim3(128 * 8), dim3(256), 0, stream,
                       A, sarr, Bfrag, Ext, yp, rsp, ssp, wsp);
  } else {
    hipLaunchKernelGGL((fused_attn_kernel<32>), dim3(128 * 4), dim3(256), 0, stream,
                       A, sarr, Bfrag, Ext, yp, rsp, ssp, wsp);
  }
  hipLaunchKernelGGL(finish_kernel, dim3(2048), dim3(256), 0, stream,
                     x2, sqarr, yp, rsp, ssp, wsp, Wg, bg, W2, b2, out, l1c, l2c, jsplit);
  hipLaunchKernelGGL(loss_kernel, dim3(1), dim3(256), 0, stream, l1c, l2c, out);
}

// Round 8
// 169.793 us; speedup vs baseline: 1.2641x; 1.1130x over previous
//
#include <hip/hip_runtime.h>
#include <hip/hip_bf16.h>
#include <cstddef>
#include <cstdint>

#define NROWS 8192
#define LOG2E 1.4426950408889634f

typedef __attribute__((ext_vector_type(8))) short bf16x8;
typedef __attribute__((ext_vector_type(4))) float f32x4;
typedef __attribute__((ext_vector_type(16))) float f32x16;

#define EXP2(x) __builtin_amdgcn_exp2f(x)

__device__ __forceinline__ short f2bf(float f) {
  unsigned u = __float_as_uint(f);
  u += 0x7fffu + ((u >> 16) & 1u);   // RNE
  return (short)(u >> 16);
}
__device__ __forceinline__ float leaky_f(float v) { return fmaxf(v, 0.1f * v); }

union BFPair { __hip_bfloat162 h; unsigned u; };
__device__ __forceinline__ unsigned pack2(float a, float b) {
  BFPair p;
  p.h = __float22bfloat162_rn(make_float2(a, b));  // v_cvt_pk_bf16_f32
  return p.u;
}

// ---------------- Kernel 1: MLP encoder: x[8192,256] -> x2, s(prescaled), sq, x2bfT --
extern "C" __global__ void __launch_bounds__(256)
encoder_kernel(const float* __restrict__ x, const float* __restrict__ W10,
               const float* __restrict__ b10, const float* __restrict__ W11,
               const float* __restrict__ b11, const float* __restrict__ avec,
               float* __restrict__ x2, float* __restrict__ sarr,
               float* __restrict__ sqarr, short* __restrict__ x2bfT) {
  __shared__ float xr[4][256];
  __shared__ float h1[4][128];
  const int t = threadIdx.x;
  const int r0 = blockIdx.x * 4;
#pragma unroll
  for (int r = 0; r < 4; ++r) xr[r][t] = x[(size_t)(r0 + r) * 256 + t];
  __syncthreads();
  if (t < 128) {
    float acc[4];
    const float b = b10[t];
#pragma unroll
    for (int r = 0; r < 4; ++r) acc[r] = b;
    const float* wrow = W10 + t * 256;
    for (int c = 0; c < 256; c += 4) {
      const float4 wv = *(const float4*)(wrow + c);
#pragma unroll
      for (int r = 0; r < 4; ++r) {
        acc[r] = fmaf(wv.x, xr[r][c], acc[r]);
        acc[r] = fmaf(wv.y, xr[r][c + 1], acc[r]);
        acc[r] = fmaf(wv.z, xr[r][c + 2], acc[r]);
        acc[r] = fmaf(wv.w, xr[r][c + 3], acc[r]);
      }
    }
#pragma unroll
    for (int r = 0; r < 4; ++r) h1[r][t] = leaky_f(acc[r]);
  }
  __syncthreads();
  if (t < 64) {
    float acc[4];
    const float b = b11[t];
#pragma unroll
    for (int r = 0; r < 4; ++r) acc[r] = b;
    const float* wrow = W11 + t * 128;
    for (int c = 0; c < 128; c += 4) {
      const float4 wv = *(const float4*)(wrow + c);
#pragma unroll
      for (int r = 0; r < 4; ++r) {
        acc[r] = fmaf(wv.x, h1[r][c], acc[r]);
        acc[r] = fmaf(wv.y, h1[r][c + 1], acc[r]);
        acc[r] = fmaf(wv.z, h1[r][c + 2], acc[r]);
        acc[r] = fmaf(wv.w, h1[r][c + 3], acc[r]);
      }
    }
    const float av = avec[t];
#pragma unroll
    for (int r = 0; r < 4; ++r) {
      const float v = leaky_f(acc[r]);
      x2[(size_t)(r0 + r) * 64 + t] = v;
      x2bfT[(size_t)t * NROWS + r0 + r] = f2bf(v);
      float ps = v * av, pq = v * v;
#pragma unroll
      for (int off = 1; off < 64; off <<= 1) {
        ps += __shfl_xor(ps, off);
        pq += __shfl_xor(pq, off);
      }
      if (t == 0) {
        sarr[r0 + r] = ps * LOG2E;          // exp(leaky(d)) = exp2(leaky(d*log2e))
        sqarr[r0 + r] = pq * (1.0f / 64.0f);
      }
    }
  }
}

// ---------------- Kernel 1b: B/Ext fragments for 32x32x16 MFMA ----------------------
// Bfrag[Sg][h][lane][8]: x2^T[n = h*32 + (lane&31)][k = Sg*16 + (lane>>5)*8 + e]
// Ext[Sg][lane][8]: col0 = 1.0 (rowsum), col1 = sq_k (wsq), else 0
extern "C" __global__ void __launch_bounds__(256)
prep32_kernel(const short* __restrict__ x2bfT, const float* __restrict__ sqarr,
              short* __restrict__ Bfrag, short* __restrict__ Ext) {
  const int Sg = blockIdx.x;           // 512 groups of k=16
  const int t = threadIdx.x;
  const int q = t >> 6, l = t & 63;
  const int col = l & 31, kg = l >> 5;
  if (q < 2) {
    const bf16x8 v = *(const bf16x8*)(x2bfT + (size_t)(q * 32 + col) * NROWS + Sg * 16 + kg * 8);
    *(bf16x8*)(Bfrag + ((size_t)Sg * 2 + q) * 512 + l * 8) = v;
  } else if (q == 2) {
    bf16x8 e;
    if (col == 0) {
#pragma unroll
      for (int i = 0; i < 8; ++i) e[i] = (short)0x3F80;   // bf16 1.0
    } else if (col == 1) {
#pragma unroll
      for (int i = 0; i < 8; ++i) e[i] = f2bf(sqarr[Sg * 16 + kg * 8 + i]);
    } else {
#pragma unroll
      for (int i = 0; i < 8; ++i) e[i] = 0;
    }
    *(bf16x8*)(Ext + (size_t)Sg * 512 + l * 8) = e;
  }
}

// ---------------- Kernel 2: fused A-pass, pure-linear streaming ----------------------
// Wave owns 32 rows. Per 256-col chunk: phase E = 32 rolling 1KB SEQUENTIAL row-loads
// (each instruction one contiguous run; chunks advance sequentially down each row),
// exp2 in regs, XOR-swizzled scatter into wave-private LDS fragments (no barriers).
// Phase M = 16 x {swizzled ds_read_b128 A-frag, L2-hot B/Ext frag loads (rolled 2-S,
// counted vmcnt), 4 x mfma_32x32x16}. rowsum/wsq via Ext columns; sumsq via diag.

#define LDG4(dst, ptr) \
  asm volatile("global_load_dwordx4 %0, %1, off" : "=&v"(dst) : "v"(ptr) : "memory")
#define VMCNTI(n) \
  do { asm volatile("s_waitcnt vmcnt(%0)" :: "i"(n) : "memory"); \
       __builtin_amdgcn_sched_barrier(0); } while (0)

extern "C" __global__ void __launch_bounds__(256, 2)
fused_lin_kernel(const float* __restrict__ A, const float* __restrict__ sarr,
                 const short* __restrict__ Bfrag, const short* __restrict__ Ext,
                 float* __restrict__ yp, float* __restrict__ rsp,
                 float* __restrict__ ssp, float* __restrict__ wsp,
                 int ks_shift, int nchunks) {
  __shared__ __attribute__((aligned(16))) short frag[4][8192];  // per-wave 16 frags x 1KB
  __shared__ __attribute__((aligned(16))) float sjbuf[2048];
  __shared__ float sibuf[128];

  const int t = threadIdx.x;
  const int l = t & 63;
  const int w = __builtin_amdgcn_readfirstlane(t >> 6);
  const int bid = blockIdx.x;
  const int js = bid & ((1 << ks_shift) - 1);
  const int rg = bid >> ks_shift;
  const int jspan = nchunks << 8;
  const int jb = js * jspan;
  const int rowbase = rg * 128 + w * 32;

  for (int k = t; k < jspan; k += 256) sjbuf[k] = sarr[jb + k];
  if (t < 128) sibuf[t] = sarr[rg * 128 + t];
  __syncthreads();   // the only barrier

  short* myf = frag[w];
  char*  myfb = (char*)myf;
  // E-write swizzle constants: lane l covers frag s_l = l>>2, k-half hl, byte-half bo
  const int s_l = l >> 2;
  const int hl32 = ((l >> 1) & 1) * 32;
  const int ssw = s_l & 7;
  const int ebase = s_l * 1024 + (l & 1) * 8;

  f32x16 accY0 = {}, accY1 = {}, accE = {}, accD = {};

#pragma unroll 1
  for (int ch = 0; ch < nchunks; ++ch) {
    // ---- phase E: linear stream + exp + LDS fragment scatter ----
    const float* aBase = A + (size_t)rowbase * NROWS + jb + ch * 256 + (size_t)l * 4;
    f32x4 aval[8];
#pragma unroll
    for (int r = 0; r < 6; ++r) LDG4(aval[r & 7], aBase + (size_t)r * NROWS);
    const f32x4 sjv = *(const f32x4*)(sjbuf + ch * 256 + l * 4);
#pragma unroll
    for (int r = 0; r < 32; ++r) {
      if (r + 6 < 32) LDG4(aval[(r + 6) & 7], aBase + (size_t)(r + 6) * NROWS);
      VMCNTI((31 - r) < 6 ? (31 - r) : 6);
      const f32x4 a4 = aval[r & 7];
      const float si_r = sibuf[w * 32 + r];
      const float d0 = si_r - sjv[0], d1 = si_r - sjv[1];
      const float d2 = si_r - sjv[2], d3 = si_r - sjv[3];
      const float r0 = EXP2(fmaxf(d0, 0.1f * d0)) * a4[0];
      const float r1 = EXP2(fmaxf(d1, 0.1f * d1)) * a4[1];
      const float r2 = EXP2(fmaxf(d2, 0.1f * d2)) * a4[2];
      const float r3 = EXP2(fmaxf(d3, 0.1f * d3)) * a4[3];
      uint2 pk;
      pk.x = pack2(r0, r1);
      pk.y = pack2(r2, r3);
      *(uint2*)(myfb + ebase + ((((r + hl32) ^ ssw)) << 4)) = pk;
    }
    // wave-private LDS: order E-writes before M-reads (no barrier needed)
    asm volatile("s_waitcnt lgkmcnt(0)" ::: "memory");
    __builtin_amdgcn_sched_barrier(0);

    // ---- phase M: fragment MFMA with rolled L2-hot B/Ext loads ----
    const size_t Sg0 = (size_t)(jb >> 4) + (size_t)ch * 16;
    const short* bB = Bfrag + Sg0 * 1024 + l * 8;
    const short* eB = Ext + Sg0 * 512 + l * 8;
    bf16x8 rb0[4], rb1[4], re[4];
#pragma unroll
    for (int s = 0; s < 2; ++s) {
      LDG4(rb0[s], bB + s * 1024);
      LDG4(rb1[s], bB + s * 1024 + 512);
      LDG4(re[s],  eB + s * 512);
    }
#pragma unroll
    for (int s = 0; s < 16; ++s) {
      if (s + 2 < 16) {
        LDG4(rb0[(s + 2) & 3], bB + (s + 2) * 1024);
        LDG4(rb1[(s + 2) & 3], bB + (s + 2) * 1024 + 512);
        LDG4(re[(s + 2) & 3],  eB + (s + 2) * 512);
      }
      VMCNTI(3 * (15 - s) < 6 ? 3 * (15 - s) : 6);
      const bf16x8 ar = *(const bf16x8*)(myf + s * 512 + ((l ^ (s & 7)) << 3));
      accY0 = __builtin_amdgcn_mfma_f32_32x32x16_bf16(ar, rb0[s & 3], accY0, 0, 0, 0);
      accY1 = __builtin_amdgcn_mfma_f32_32x32x16_bf16(ar, rb1[s & 3], accY1, 0, 0, 0);
      accE  = __builtin_amdgcn_mfma_f32_32x32x16_bf16(ar, re[s & 3],  accE, 0, 0, 0);
      accD  = __builtin_amdgcn_mfma_f32_32x32x16_bf16(ar, ar,         accD, 0, 0, 0);
    }
  }

  // ---- epilogue: 32x32 C/D layout: col = lane&31, row = (reg&3)+8*(reg>>2)+4*(lane>>5)
  float* ypb = yp + (size_t)js * NROWS * 64;
  const int cc = l & 31;
  const int rhi = (l >> 5) * 4;
#pragma unroll
  for (int reg = 0; reg < 16; ++reg) {
    const int rl = (reg & 3) + 8 * (reg >> 2) + rhi;
    const int grow = rowbase + rl;
    ypb[(size_t)grow * 64 + cc]      = accY0[reg];
    ypb[(size_t)grow * 64 + 32 + cc] = accY1[reg];
    if (cc == 0) rsp[js * NROWS + grow] = accE[reg];
    if (cc == 1) wsp[js * NROWS + grow] = accE[reg];
    if (rl == cc) ssp[js * NROWS + rowbase + cc] = accD[reg];
  }
}

// ---------------- Kernel 3: combine partials, GNN layer + head, per-row losses ------
extern "C" __global__ void __launch_bounds__(256)
finish_kernel(const float* __restrict__ x2, const float* __restrict__ sqarr,
              const float* __restrict__ yp, const float* __restrict__ rsp,
              const float* __restrict__ ssp, const float* __restrict__ wsp,
              const float* __restrict__ Wg, const float* __restrict__ bg,
              const float* __restrict__ W2, const float* __restrict__ b2,
              float* __restrict__ outp, float* __restrict__ l1c, float* __restrict__ l2c,
              int jsplit) {
  __shared__ float hbuf[4][64];
  __shared__ float gbuf[4][64];
  const int t = threadIdx.x;
  const int w = t >> 6, lane = t & 63;
  const int i = blockIdx.x * 4 + w;

  float yv = 0.f, rowsum = 0.f, sumsq = 0.f, wsq = 0.f;
#pragma unroll 4
  for (int p = 0; p < jsplit; ++p) {
    yv += yp[(size_t)p * NROWS * 64 + (size_t)i * 64 + lane];
    rowsum += rsp[p * NROWS + i];
    sumsq += ssp[p * NROWS + i];
    wsq += wsp[p * NROWS + i];
  }
  const float inv = 1.0f / rowsum;
  hbuf[w][lane] = yv * inv;
  const float xv = x2[(size_t)i * 64 + lane];
  float xy = xv * yv;
#pragma unroll
  for (int off = 1; off < 64; off <<= 1) xy += __shfl_xor(xy, off);
  if (lane == 0) {
    l1c[i] = sqarr[i] + (wsq - (2.0f / 64.0f) * xy) * inv;
    l2c[i] = sumsq * inv * inv;
  }
  __syncthreads();
  float accg = bg[lane];
  {
    const float* wrow = Wg + lane * 64;
#pragma unroll 4
    for (int d = 0; d < 64; ++d) accg = fmaf(wrow[d], hbuf[w][d], accg);
  }
  gbuf[w][lane] = leaky_f(accg);
  __syncthreads();
  if (lane < 32) {
    float acco = b2[lane];
    const float* wrow = W2 + lane * 64;
#pragma unroll 4
    for (int d = 0; d < 64; ++d) acco = fmaf(wrow[d], gbuf[w][d], acco);
    outp[(size_t)i * 32 + lane] = acco;
  }
}

// ---------------- Kernel 4: scalar loss reduction -----------------------------------
extern "C" __global__ void __launch_bounds__(256)
loss_kernel(const float* __restrict__ l1c, const float* __restrict__ l2c,
            float* __restrict__ outp) {
  __shared__ float s1[256], s2[256];
  const int t = threadIdx.x;
  float a1 = 0.f, a2 = 0.f;
  for (int i = t * 4; i < NROWS; i += 1024) {
    const float4 v1 = *(const float4*)(l1c + i);
    const float4 v2 = *(const float4*)(l2c + i);
    a1 += (v1.x + v1.y) + (v1.z + v1.w);
    a2 += (v2.x + v2.y) + (v2.z + v2.w);
  }
  s1[t] = a1; s2[t] = a2;
  __syncthreads();
  for (int off = 128; off > 0; off >>= 1) {
    if (t < off) { s1[t] += s1[t + off]; s2[t] += s2[t + off]; }
    __syncthreads();
  }
  if (t == 0) {
    const float scale = 1.0f / ((float)NROWS * (float)NROWS);
    outp[NROWS * 32] = s1[0] * scale;
    outp[NROWS * 32 + 1] = s2[0] * scale;
  }
}

// ---------------- launch ------------------------------------------------------------
extern "C" void kernel_launch(void* const* d_in, const int* in_sizes, int n_in,
                              void* d_out, int out_size, void* d_ws, size_t ws_size,
                              hipStream_t stream) {
  const float* x   = (const float*)d_in[0];
  const float* A   = (const float*)d_in[1];
  const float* W10 = (const float*)d_in[2];
  const float* b10 = (const float*)d_in[3];
  const float* W11 = (const float*)d_in[4];
  const float* b11 = (const float*)d_in[5];
  const float* av  = (const float*)d_in[6];
  const float* Wg  = (const float*)d_in[7];
  const float* bg  = (const float*)d_in[8];
  const float* W2  = (const float*)d_in[9];
  const float* b2  = (const float*)d_in[10];
  float* out = (float*)d_out;

  const size_t fixed_floats = (size_t)NROWS * 64 + 4 * (size_t)NROWS;
  auto need = [&](int ks) {
    return (fixed_floats + (size_t)ks * NROWS * 64 + 3 * (size_t)ks * NROWS) * 4
           + (size_t)NROWS * 64 * 2      // x2bfT
           + (size_t)512 * 1024 * 2      // Bfrag32
           + (size_t)512 * 512 * 2;      // Ext32
  };
  const int ks_shift = (ws_size >= need(8)) ? 3 : 2;
  const int ksplit = 1 << ks_shift;
  const int nchunks = (NROWS / ksplit) >> 8;   // 4 (ks=8) or 8 (ks=4)

  float* ws    = (float*)d_ws;
  float* x2    = ws;                                        // N*64
  float* sarr  = x2 + (size_t)NROWS * 64;                   // N (prescaled by log2 e)
  float* sqarr = sarr + NROWS;                              // N
  float* yp    = sqarr + NROWS;                             // ksplit*N*64
  float* rsp   = yp + (size_t)ksplit * NROWS * 64;          // ksplit*N
  float* ssp   = rsp + (size_t)ksplit * NROWS;              // ksplit*N
  float* wsp   = ssp + (size_t)ksplit * NROWS;              // ksplit*N
  float* l1c   = wsp + (size_t)ksplit * NROWS;              // N
  float* l2c   = l1c + NROWS;                               // N
  short* x2bfT = (short*)(l2c + NROWS);                     // N*64 bf16 (transposed)
  short* Bfrag = x2bfT + (size_t)NROWS * 64;                // 512*2*512 bf16 (1MB)
  short* Ext   = Bfrag + (size_t)512 * 1024;                // 512*512 bf16 (512KB)

  hipLaunchKernelGGL(encoder_kernel, dim3(2048), dim3(256), 0, stream,
                     x, W10, b10, W11, b11, av, x2, sarr, sqarr, x2bfT);
  hipLaunchKernelGGL(prep32_kernel, dim3(512), dim3(256), 0, stream,
                     x2bfT, sqarr, Bfrag, Ext);
  hipLaunchKernelGGL(fused_lin_kernel, dim3(64 * ksplit), dim3(256), 0, stream,
                     A, sarr, Bfrag, Ext, yp, rsp, ssp, wsp, ks_shift, nchunks);
  hipLaunchKernelGGL(finish_kernel, dim3(2048), dim3(256), 0, stream,
                     x2, sqarr, yp, rsp, ssp, wsp, Wg, bg, W2, b2, out, l1c, l2c, ksplit);
  hipLaunchKernelGGL(loss_kernel, dim3(1), dim3(256), 0, stream, l1c, l2c, out);
}